// Round 9
// baseline (284.012 us; speedup 1.0000x reference)
//
#include <hip/hip_runtime.h>
#include <hip/hip_bf16.h>

#define NA   312      // attributes
#define LAT  64       // latent per attribute (K)
#define HID  128      // hidden per attribute (N)
#define NB   8192     // batch
#define AG   8        // attributes per block
#define NAG  (NA / AG)    // 39 attribute groups
#define RB   32       // rows per block
#define NBT  (NB / RB)    // 256 batch tiles

typedef __attribute__((ext_vector_type(8))) short bf16x8;
typedef __attribute__((ext_vector_type(4))) float f32x4;

// fp32 -> bf16 RNE scalar (prep kernel only)
__device__ inline short f2bf(float f) {
    unsigned u = __builtin_bit_cast(unsigned, f);
    u += 0x7FFFu + ((u >> 16) & 1u);
    return (short)(u >> 16);
}

// 8x fp32 -> bf16x8; __float22bfloat162_rn lowers to v_cvt_pk_bf16_f32.
__device__ inline bf16x8 pack8(float4 v0, float4 v1) {
    __hip_bfloat162 c[4] = {
        __float22bfloat162_rn(float2{v0.x, v0.y}),
        __float22bfloat162_rn(float2{v0.z, v0.w}),
        __float22bfloat162_rn(float2{v1.x, v1.y}),
        __float22bfloat162_rn(float2{v1.z, v1.w})};
    bf16x8 f;
    __builtin_memcpy(&f, &c[0], 16);
    return f;
}

// ---------------- prep: W1 [A][LAT][HID] fp32 -> frag-ordered bf16 ----------
// frag entry e = (nt*2+kk)*64 + lane holds 8 bf16:
//   element j = W1[a][ kk*32 + (lane>>4)*8 + j ][ nt*16 + (lane&15) ]
__global__ __launch_bounds__(256, 2) void prep_w1(
    const float* __restrict__ W1, short* __restrict__ w1f)
{
    __shared__ float lds[LAT * HID];   // 32 KB fp32
    const int a   = blockIdx.x;
    const int tid = threadIdx.x;

    const float4* src = reinterpret_cast<const float4*>(W1 + (size_t)a * (LAT * HID));
    float4* ldsv = reinterpret_cast<float4*>(lds);
    #pragma unroll
    for (int i = 0; i < (LAT * HID / 4) / 256; ++i)
        ldsv[i * 256 + tid] = src[i * 256 + tid];
    __syncthreads();

    bf16x8* dst = reinterpret_cast<bf16x8*>(w1f + (size_t)a * (LAT * HID));
    #pragma unroll
    for (int i = 0; i < 4; ++i) {
        const int e    = i * 256 + tid;
        const int nt   = e >> 7;
        const int kk   = (e >> 6) & 1;
        const int lane = e & 63;
        const int n  = nt * 16 + (lane & 15);
        const int k0 = kk * 32 + (lane >> 4) * 8;
        bf16x8 f;
        #pragma unroll
        for (int j = 0; j < 8; ++j)
            f[j] = f2bf(lds[(k0 + j) * HID + n]);
        dst[e] = f;
    }
}

// ---------------- main: 2KB-granule DMA stage, wave-per-attr compute --------
// Block = 32 rows x 8 attrs, 512 threads (8 waves). Stage: global_load_lds
// width-16 pulls each row's 2 KB span contiguously into linear LDS (fp32),
// with the XOR swizzle applied to the GLOBAL source chunk index (m173).
// Compute: wave w owns attr w (B:x traffic 1:1, B L1/L2-resident), A-frags
// from LDS with the matching XOR (2-way conflicts = free).
__global__ __launch_bounds__(512, 4) void attr_decoder_main(
    const float* __restrict__ x,
    const short* __restrict__ w1f,
    const float* __restrict__ b1,
    const float* __restrict__ W2,
    const float* __restrict__ b2,
    float* __restrict__ out)
{
    __shared__ float xs[RB * AG * LAT];   // 32 rows x 512 fp32 = 64 KB

    const int tid  = threadIdx.x;
    const unsigned g = blockIdx.x;
    const int ag   = g % NAG;             // ag-fast: co-resident blocks span a
    const int bt   = g / NAG;             //          dense ~160 MB row band
    const int row0 = bt * RB;
    const int w    = tid >> 6;
    const int lane = tid & 63;

    // ---- stage: wave w DMAs rows w*4..w*4+3 (2 KB each) into LDS ----
    #pragma unroll
    for (int i = 0; i < 8; ++i) {
        const int r = w * 4 + (i >> 1);            // local row (uniform per wave)
        const int p = (i & 1) * 64 + lane;         // phys 16B slot within row
        const int c = p ^ (r & 7);                 // pre-swizzled global chunk
        const float* src = x + (size_t)(row0 + r) * (NA * LAT)
                             + ag * (AG * LAT) + c * 4;
        __builtin_amdgcn_global_load_lds(
            (const __attribute__((address_space(1))) unsigned*)src,
            (__attribute__((address_space(3))) unsigned*)&xs[r * (AG * LAT) + (i & 1) * 256],
            16, 0, 0);
    }
    asm volatile("s_waitcnt vmcnt(0)" ::: "memory");
    __syncthreads();

    const int llo = lane & 15;
    const int lhi = lane >> 4;
    const int al  = w;                  // wave's attribute (local)
    const int a   = ag * AG + al;

    // ---- A-frags from LDS (XOR-matched reads, then packed cvt) ----
    bf16x8 af[2][2];
    #pragma unroll
    for (int mt = 0; mt < 2; ++mt) {
        const int r = mt * 16 + llo;
        const float* rowp = xs + r * (AG * LAT);
        const int e = r & 7;
        #pragma unroll
        for (int kk = 0; kk < 2; ++kk) {
            const int c0 = al * 16 + kk * 8 + lhi * 2;   // even logical slot
            const float4 v0 = *reinterpret_cast<const float4*>(rowp + (size_t)((c0       ^ e) * 4));
            const float4 v1 = *reinterpret_cast<const float4*>(rowp + (size_t)(((c0 + 1) ^ e) * 4));
            af[mt][kk] = pack8(v0, v1);
        }
    }

    // ---- layer 1 MFMA + fused layer-2 partials ----
    const bf16x8* wf  = reinterpret_cast<const bf16x8*>(w1f + (size_t)a * (LAT * HID));
    const float*  b1a = b1 + a * HID;
    const float*  w2a = W2 + a * HID;
    float p2[2][4] = {};
    #pragma unroll
    for (int nt = 0; nt < 8; ++nt) {
        const bf16x8 bf0 = wf[(nt * 2 + 0) * 64 + lane];
        const bf16x8 bf1 = wf[(nt * 2 + 1) * 64 + lane];
        const int n = nt * 16 + llo;
        const float b1v = b1a[n];
        const float w2v = w2a[n];
        #pragma unroll
        for (int mt = 0; mt < 2; ++mt) {
            f32x4 acc = {b1v, b1v, b1v, b1v};
            acc = __builtin_amdgcn_mfma_f32_16x16x32_bf16(af[mt][0], bf0, acc, 0, 0, 0);
            acc = __builtin_amdgcn_mfma_f32_16x16x32_bf16(af[mt][1], bf1, acc, 0, 0, 0);
            #pragma unroll
            for (int r = 0; r < 4; ++r)
                p2[mt][r] = fmaf(fmaxf(acc[r], 0.f), w2v, p2[mt][r]);
        }
    }

    // ---- in-wave reduction over n-lanes, sigmoid, store ----
    const float ob = b2[a];
    #pragma unroll
    for (int mt = 0; mt < 2; ++mt) {
        #pragma unroll
        for (int r = 0; r < 4; ++r) {
            float s = p2[mt][r];
            s += __shfl_xor(s, 1);
            s += __shfl_xor(s, 2);
            s += __shfl_xor(s, 4);
            s += __shfl_xor(s, 8);
            s = 1.0f / (1.0f + __expf(-(s + ob)));
            if (llo == 0) {
                const int row = row0 + mt * 16 + lhi * 4 + r;
                out[(size_t)row * NA + a] = s;
            }
        }
    }
}

extern "C" void kernel_launch(void* const* d_in, const int* in_sizes, int n_in,
                              void* d_out, int out_size, void* d_ws, size_t ws_size,
                              hipStream_t stream) {
    const float* x  = (const float*)d_in[0];
    const float* W1 = (const float*)d_in[1];
    const float* b1 = (const float*)d_in[2];
    const float* W2 = (const float*)d_in[3];
    const float* b2 = (const float*)d_in[4];
    float* out = (float*)d_out;
    short* w1f = (short*)d_ws;          // 312*8192 bf16 = 5.1 MB

    hipLaunchKernelGGL(prep_w1, dim3(NA), dim3(256), 0, stream, W1, w1f);
    hipLaunchKernelGGL(attr_decoder_main, dim3(NAG * NBT), dim3(512), 0, stream,
                       x, w1f, b1, W2, b2, out);
}